// Round 18
// baseline (136.484 us; speedup 1.0000x reference)
//
#include <hip/hip_runtime.h>
#include <hip/hip_bf16.h>

#define N_NODES 50000
#define NPAD 50016          // Yc row stride: N_NODES padded; rows >= N_NODES are zero
#define DUMMY 50000         // dummy src index -> zero row (padding contributes 0)
#define DIM 256
#define N_EDGES 1600000
#define NBUK 196            // buckets of 256 nodes: 196*256 = 50176 >= 50000
#define CAP 10240           // fixed bucket region capacity (8-padded mean ~9060 + 12 sigma)
#define CHUNK_E 4096        // edges per binning block
#define NBLK ((N_EDGES + CHUNK_E - 1) / CHUNK_E)   // 391
#define GEMM_BLKS ((N_NODES + 63) / 64)            // 782
#define NCHUNK 8            // Y column chunks (32 cols each), one per XCD
#define AGG_BPC 391         // aggregate blocks per chunk (512 thr = 8 warps = 8 groups)
#define NGROUP (N_NODES / 16)  // 3125 groups of 16 nodes
#define LROW 72             // LDS W-tile row stride in bf16 (144 B, not 0 mod 128B)

typedef float f32x4 __attribute__((ext_vector_type(4)));
typedef __bf16 bf16x8 __attribute__((ext_vector_type(8)));
typedef __bf16 bf16x4 __attribute__((ext_vector_type(4)));
typedef unsigned long long u64;
typedef unsigned int u32;
typedef unsigned short u16;

// ================= K1: place (391 blocks) || gemm (782 blocks) ================
// Independent roles: place reads src/dst; gemm reads W (f32, converted during
// LDS staging -- no Wbf intermediate) + feat. gemm block 0 zeroes Yc pad rows.
__global__ __launch_bounds__(256) void k1_k(const float* __restrict__ feat,
                                            const float* __restrict__ W,
                                            __bf16* __restrict__ Yc,
                                            const int* __restrict__ src,
                                            const int* __restrict__ dst,
                                            int* __restrict__ bcur,
                                            unsigned int* __restrict__ staged) {
    __shared__ __bf16 lw[256 * LROW];    // 36 KB W K-quarter tile (gemm role)
    int* lh    = (int*)lw;               // place role aliases
    int* lbase = lh + NBUK;

    if (blockIdx.x < NBLK) {
        // ---- place role ----
        int pb = blockIdx.x;
        for (int i = threadIdx.x; i < NBUK; i += 256) lh[i] = 0;
        __syncthreads();
        int base = pb * CHUNK_E;
        int end = base + CHUNK_E; if (end > N_EDGES) end = N_EDGES;
        for (int e = base + threadIdx.x; e < end; e += 256)
            atomicAdd(&lh[dst[e] >> 8], 1);
        __syncthreads();
        for (int i = threadIdx.x; i < NBUK; i += 256) {
            int c = lh[i];
            lbase[i] = c ? (atomicAdd(&bcur[i], c) + i * CAP) : 0;
            lh[i] = 0;                 // reuse as local cursor
        }
        __syncthreads();
        for (int e = base + threadIdx.x; e < end; e += 256) {
            int d = dst[e];
            int s = src[e];            // < 50000 -> fits in 16 bits
            int b = d >> 8;
            int p = atomicAdd(&lh[b], 1);
            staged[lbase[b] + p] = (unsigned int)s | ((unsigned int)(d & 255) << 16);
        }
    } else {
        // ---- GEMM role ----
        const int gb   = blockIdx.x - NBLK;
        const int wid  = threadIdx.x >> 6;
        const int lane = threadIdx.x & 63;
        const int row0 = gb * 64 + wid * 16;
        const int mrow = lane & 15;
        const int kgrp = lane >> 4;          // 0..3

        int arow = row0 + mrow;
        int arow_c = arow < N_NODES ? arow : (N_NODES - 1);
        const float* aptr = feat + (size_t)arow_c * DIM + kgrp * 8;

        const int t = threadIdx.x;
        const int srow = t >> 3;             // base row (stride 32 per iter)
        const int scb  = (t & 7) * 8;        // col offset within quarter

        if (gb == 0) {                       // zero Yc pad rows (4096 elems)
            for (int i = threadIdx.x; i < NCHUNK * 16 * 32; i += 256) {
                int c = i >> 9;
                int rem = i & 511;
                Yc[(size_t)c * NPAD * 32 + (size_t)(N_NODES + (rem >> 5)) * 32 + (rem & 31)]
                    = (__bf16)0.0f;
            }
        }

        f32x4 acc[16];
#pragma unroll
        for (int i = 0; i < 16; ++i) acc[i] = (f32x4)0.0f;

        for (int p = 0; p < 4; ++p) {
            f32x4 ar0 = *(const f32x4*)(aptr + (p * 2) * 32);
            f32x4 ar1 = *(const f32x4*)(aptr + (p * 2) * 32 + 4);
            f32x4 ar2 = *(const f32x4*)(aptr + (p * 2 + 1) * 32);
            f32x4 ar3 = *(const f32x4*)(aptr + (p * 2 + 1) * 32 + 4);

            if (p) __syncthreads();
            // stage W[:, p*64..+64) f32 -> bf16 LDS
#pragma unroll
            for (int i = 0; i < 8; ++i) {
                int row = srow + i * 32;
                const float* wp = W + (size_t)row * DIM + p * 64 + scb;
                f32x4 w0 = *(const f32x4*)(wp);
                f32x4 w1 = *(const f32x4*)(wp + 4);
                bf16x8 wv;
                wv[0] = (__bf16)w0[0]; wv[1] = (__bf16)w0[1];
                wv[2] = (__bf16)w0[2]; wv[3] = (__bf16)w0[3];
                wv[4] = (__bf16)w1[0]; wv[5] = (__bf16)w1[1];
                wv[6] = (__bf16)w1[2]; wv[7] = (__bf16)w1[3];
                *(bf16x8*)(lw + row * LROW + scb) = wv;
            }
            __syncthreads();

            bf16x8 af0, af1;
            af0[0] = (__bf16)ar0[0]; af0[1] = (__bf16)ar0[1];
            af0[2] = (__bf16)ar0[2]; af0[3] = (__bf16)ar0[3];
            af0[4] = (__bf16)ar1[0]; af0[5] = (__bf16)ar1[1];
            af0[6] = (__bf16)ar1[2]; af0[7] = (__bf16)ar1[3];
            af1[0] = (__bf16)ar2[0]; af1[1] = (__bf16)ar2[1];
            af1[2] = (__bf16)ar2[2]; af1[3] = (__bf16)ar2[3];
            af1[4] = (__bf16)ar3[0]; af1[5] = (__bf16)ar3[1];
            af1[6] = (__bf16)ar3[2]; af1[7] = (__bf16)ar3[3];

#pragma unroll
            for (int nt = 0; nt < 16; ++nt) {
                const __bf16* lp = lw + (nt * 16 + mrow) * LROW + kgrp * 8;
                bf16x8 wf0 = *(const bf16x8*)(lp);
                bf16x8 wf1 = *(const bf16x8*)(lp + 32);
                acc[nt] = __builtin_amdgcn_mfma_f32_16x16x32_bf16(wf0, af0, acc[nt], 0, 0, 0);
                acc[nt] = __builtin_amdgcn_mfma_f32_16x16x32_bf16(wf1, af1, acc[nt], 0, 0, 0);
            }
        }

        const int node = row0 + mrow;
        if (node < N_NODES) {
#pragma unroll
            for (int nt = 0; nt < 16; ++nt) {
                int oc0 = nt * 16 + kgrp * 4;
                bf16x4 pv;
                pv[0] = (__bf16)acc[nt][0];
                pv[1] = (__bf16)acc[nt][1];
                pv[2] = (__bf16)acc[nt][2];
                pv[3] = (__bf16)acc[nt][3];
                __bf16* yp = Yc + (size_t)(oc0 >> 5) * NPAD * 32
                                + (size_t)node * 32 + (oc0 & 31);
                *(bf16x4*)yp = pv;
            }
        }
    }
}

// ================= K2: finalize (1024 threads/block, 196 blocks) ==============
// Node offsets/degrees + u16 edge lists, 8-padded with DUMMY.
__global__ __launch_bounds__(1024) void finalize_k(const unsigned int* __restrict__ staged,
                                                   const int* __restrict__ bcur,
                                                   int* __restrict__ offs,
                                                   u16* __restrict__ deg16,
                                                   u16* __restrict__ edge16) {
    __shared__ int nh[256];
    __shared__ int nbase[256];
    __shared__ int sm[256];
    int t = threadIdx.x, b = blockIdx.x;
    int beg = b * CAP;
    int cnt = bcur[b];
    if (t < 256) nh[t] = 0;
    __syncthreads();
    for (int i = t; i < cnt; i += 1024)
        atomicAdd(&nh[staged[beg + i] >> 16], 1);
    __syncthreads();
    int v = (t < 256) ? nh[t] : 0;
    int v8 = (v + 7) & ~7;         // padded count (multiple of 8)
    if (t < 256) sm[t] = v8;
    __syncthreads();
    for (int off = 1; off < 256; off <<= 1) {
        int x = (t < 256 && t >= off) ? sm[t - off] : 0;
        __syncthreads();
        if (t < 256) sm[t] += x;
        __syncthreads();
    }
    if (t < 256) {
        nbase[t] = sm[t] - v8;
        int node = (b << 8) + t;
        if (node < N_NODES) {
            offs[node]  = beg + nbase[t];
            deg16[node] = (u16)v;
        }
        for (int i = v; i < v8; ++i)
            edge16[beg + nbase[t] + i] = (u16)DUMMY;
        nh[t] = 0;                 // reuse as per-node cursor
    }
    __syncthreads();
    for (int i = t; i < cnt; i += 1024) {
        unsigned int u = staged[beg + i];
        int dl = (int)(u >> 16);
        int p = atomicAdd(&nh[dl], 1);
        edge16[beg + nbase[dl] + p] = (u16)(u & 0xFFFFu);
    }
}

// ================= K3: gather-mean + bias, dot2-accumulate, 512-thr blocks ====
// chunk = blockIdx & 7 (XCD round-robin); per-XCD working set = 3.2MB (L2-resident)
// 8 warps/block (halves block-dispatch count -> better wave residency);
// warp owns one group of 16 nodes; segment (4 lanes) owns one node (8 cols/lane).
#define GQ(ev) (*(const uint4*)(Ybase + (size_t)((u32)(ev) & 0xffffu) * 32 + cl))
#define DOT2A(acc, p) \
    asm("v_dot2_f32_bf16 %0, %1, %2, %0" : "+v"(acc) : "v"(p), "v"(ones2))
#define ACCP(qx, qy) do { \
    u32 p_; \
    p_ = __builtin_amdgcn_perm((qx).x, (qy).x, 0x05040100u); DOT2A(a0, p_); \
    p_ = __builtin_amdgcn_perm((qx).x, (qy).x, 0x07060302u); DOT2A(a1, p_); \
    p_ = __builtin_amdgcn_perm((qx).y, (qy).y, 0x05040100u); DOT2A(a2, p_); \
    p_ = __builtin_amdgcn_perm((qx).y, (qy).y, 0x07060302u); DOT2A(a3, p_); \
    p_ = __builtin_amdgcn_perm((qx).z, (qy).z, 0x05040100u); DOT2A(a4, p_); \
    p_ = __builtin_amdgcn_perm((qx).z, (qy).z, 0x07060302u); DOT2A(a5, p_); \
    p_ = __builtin_amdgcn_perm((qx).w, (qy).w, 0x05040100u); DOT2A(a6, p_); \
    p_ = __builtin_amdgcn_perm((qx).w, (qy).w, 0x07060302u); DOT2A(a7, p_); \
} while (0)

__global__ __launch_bounds__(512) void aggregate_k(const __bf16* __restrict__ Yc,
                                                   const int* __restrict__ offs,
                                                   const u16* __restrict__ deg16,
                                                   const u16* __restrict__ edge16,
                                                   const float* __restrict__ bias,
                                                   float* __restrict__ out) {
    const int chunk = blockIdx.x & 7;
    const int bic   = blockIdx.x >> 3;      // block index within chunk
    const int wid   = threadIdx.x >> 6;     // 0..7
    const int lane  = threadIdx.x & 63;
    const int seg   = lane >> 2;            // node slot 0..15
    const int cl    = (lane & 3) * 8;       // bf16 col within chunk: 0,8,16,24

    const int g = bic * 8 + wid;            // one group per warp, 8 warps/block
    if (g >= NGROUP) return;
    const int node = g * 16 + seg;

    const __bf16* Ybase = Yc + (size_t)chunk * NPAD * 32;
    const float* bp = bias + chunk * 32 + cl;
    const f32x4 bv0 = *(const f32x4*)bp;
    const f32x4 bv1 = *(const f32x4*)(bp + 4);

    const int beg = offs[node];
    const int dg  = (int)deg16[node];

    float a0 = 0.f, a1 = 0.f, a2 = 0.f, a3 = 0.f;
    float a4 = 0.f, a5 = 0.f, a6 = 0.f, a7 = 0.f;
    u32 ones2 = 0x3F803F80u;                // bf16 (1.0, 1.0)

    f32x4 r0, r1;
    if (dg > 0) {
        const int nb8 = (dg + 7) >> 3;      // number of 8-edge batches
        const int npair = nb8 >> 1;
        const int odd = nb8 & 1;
        int j = beg;
        u64 eA = *(const u64*)(edge16 + j);
        u64 eB = *(const u64*)(edge16 + j + 4);
        u64 eC = *(const u64*)(edge16 + j + 8);
        u64 eD = *(const u64*)(edge16 + j + 12);
        for (int p = 0; p < npair; ++p) {
            u64 nA = *(const u64*)(edge16 + j + 16);
            u64 nB = *(const u64*)(edge16 + j + 20);
            u64 nC = *(const u64*)(edge16 + j + 24);
            u64 nD = *(const u64*)(edge16 + j + 28);
            uint4 q0 = GQ(eA);       uint4 q1 = GQ(eA >> 16);
            uint4 q2 = GQ(eA >> 32); uint4 q3 = GQ(eA >> 48);
            uint4 q4 = GQ(eB);       uint4 q5 = GQ(eB >> 16);
            uint4 q6 = GQ(eB >> 32); uint4 q7 = GQ(eB >> 48);
            uint4 q8 = GQ(eC);       uint4 q9 = GQ(eC >> 16);
            uint4 qa = GQ(eC >> 32); uint4 qb = GQ(eC >> 48);
            uint4 qc = GQ(eD);       uint4 qd = GQ(eD >> 16);
            uint4 qe = GQ(eD >> 32); uint4 qf = GQ(eD >> 48);
            ACCP(q0, q1); ACCP(q2, q3); ACCP(q4, q5); ACCP(q6, q7);
            ACCP(q8, q9); ACCP(qa, qb); ACCP(qc, qd); ACCP(qe, qf);
            j += 16;
            eA = nA; eB = nB; eC = nC; eD = nD;
        }
        if (odd) {
            uint4 q0 = GQ(eA);       uint4 q1 = GQ(eA >> 16);
            uint4 q2 = GQ(eA >> 32); uint4 q3 = GQ(eA >> 48);
            uint4 q4 = GQ(eB);       uint4 q5 = GQ(eB >> 16);
            uint4 q6 = GQ(eB >> 32); uint4 q7 = GQ(eB >> 48);
            ACCP(q0, q1); ACCP(q2, q3); ACCP(q4, q5); ACCP(q6, q7);
        }
        float inv = 1.0f / (float)dg;
        r0[0] = a0 * inv + bv0[0];
        r0[1] = a1 * inv + bv0[1];
        r0[2] = a2 * inv + bv0[2];
        r0[3] = a3 * inv + bv0[3];
        r1[0] = a4 * inv + bv1[0];
        r1[1] = a5 * inv + bv1[1];
        r1[2] = a6 * inv + bv1[2];
        r1[3] = a7 * inv + bv1[3];
    } else {
        uint4 q = *(const uint4*)(Ybase + (size_t)node * 32 + cl);
        r0[0] = __uint_as_float(q.x << 16) + bv0[0];
        r0[1] = __uint_as_float(q.x & 0xffff0000u) + bv0[1];
        r0[2] = __uint_as_float(q.y << 16) + bv0[2];
        r0[3] = __uint_as_float(q.y & 0xffff0000u) + bv0[3];
        r1[0] = __uint_as_float(q.z << 16) + bv1[0];
        r1[1] = __uint_as_float(q.z & 0xffff0000u) + bv1[1];
        r1[2] = __uint_as_float(q.w << 16) + bv1[2];
        r1[3] = __uint_as_float(q.w & 0xffff0000u) + bv1[3];
    }
    float* op = out + (size_t)node * DIM + chunk * 32 + cl;
    *(f32x4*)op = r0;
    *(f32x4*)(op + 4) = r1;
}

static inline size_t align64(size_t x) { return (x + 63) & ~(size_t)63; }

extern "C" void kernel_launch(void* const* d_in, const int* in_sizes, int n_in,
                              void* d_out, int out_size, void* d_ws, size_t ws_size,
                              hipStream_t stream) {
    const float* feature = (const float*)d_in[0];
    const int*   src     = (const int*)d_in[1];
    const int*   dst     = (const int*)d_in[2];
    const float* W       = (const float*)d_in[3];
    const float* b       = (const float*)d_in[4];
    float* out = (float*)d_out;

    // workspace layout (~38.2 MB total)
    char* ws = (char*)d_ws;
    __bf16* Yc  = (__bf16*)ws;               ws += align64((size_t)NCHUNK * NPAD * 32 * 2);
    int* offs     = (int*)ws;                ws += align64((size_t)N_NODES * 4);
    u16* deg16    = (u16*)ws;                ws += align64((size_t)N_NODES * 2);
    int* bcur     = (int*)ws;                ws += align64((size_t)NBUK * 4);
    unsigned int* staged = (unsigned int*)ws; ws += align64((size_t)NBUK * CAP * 4);
    u16* edge16   = (u16*)ws;                ws += align64((size_t)NBUK * CAP * 2 + 128);

    hipMemsetAsync(bcur, 0, (size_t)NBUK * 4, stream);
    k1_k<<<NBLK + GEMM_BLKS, 256, 0, stream>>>(feature, W, Yc, src, dst, bcur, staged);
    finalize_k<<<NBUK, 1024, 0, stream>>>(staged, bcur, offs, deg16, edge16);
    aggregate_k<<<NCHUNK * AGG_BPC, 512, 0, stream>>>(Yc, offs, deg16, edge16, b, out);
}

// Round 19
// 134.713 us; speedup vs baseline: 1.0131x; 1.0131x over previous
//
#include <hip/hip_runtime.h>
#include <hip/hip_bf16.h>

#define N_NODES 50000
#define NPAD 50016          // Yc row stride: N_NODES padded; rows >= N_NODES are zero
#define DUMMY 50000         // dummy src index -> zero row (padding contributes 0)
#define DIM 256
#define N_EDGES 1600000
#define NBUK 196            // buckets of 256 nodes: 196*256 = 50176 >= 50000
#define CAP 10240           // fixed bucket region capacity (8-padded mean ~9060 + 12 sigma)
#define CHUNK_E 4096        // edges per binning block
#define NBLK ((N_EDGES + CHUNK_E - 1) / CHUNK_E)   // 391
#define GEMM_BLKS ((N_NODES + 63) / 64)            // 782
#define NCHUNK 8            // Y column chunks (32 cols each), one per XCD
#define AGG_BPC 782         // aggregate blocks per chunk: 782*4 warps >= 3125 groups
#define NGROUP (N_NODES / 16)  // 3125 groups of 16 nodes
#define LROW 72             // LDS W-tile row stride in bf16 (144 B, not 0 mod 128B)

typedef float f32x4 __attribute__((ext_vector_type(4)));
typedef __bf16 bf16x8 __attribute__((ext_vector_type(8)));
typedef __bf16 bf16x4 __attribute__((ext_vector_type(4)));
typedef unsigned long long u64;
typedef unsigned int u32;
typedef unsigned short u16;

// ================= K1: place (391 blocks) || gemm (782 blocks) ================
// Independent roles: place reads src/dst; gemm reads W (f32, converted during
// LDS staging -- no Wbf intermediate) + feat. gemm block 0 zeroes Yc pad rows.
__global__ __launch_bounds__(256) void k1_k(const float* __restrict__ feat,
                                            const float* __restrict__ W,
                                            __bf16* __restrict__ Yc,
                                            const int* __restrict__ src,
                                            const int* __restrict__ dst,
                                            int* __restrict__ bcur,
                                            unsigned int* __restrict__ staged) {
    __shared__ __bf16 lw[256 * LROW];    // 36 KB W K-quarter tile (gemm role)
    int* lh    = (int*)lw;               // place role aliases
    int* lbase = lh + NBUK;

    if (blockIdx.x < NBLK) {
        // ---- place role ----
        int pb = blockIdx.x;
        for (int i = threadIdx.x; i < NBUK; i += 256) lh[i] = 0;
        __syncthreads();
        int base = pb * CHUNK_E;
        int end = base + CHUNK_E; if (end > N_EDGES) end = N_EDGES;
        for (int e = base + threadIdx.x; e < end; e += 256)
            atomicAdd(&lh[dst[e] >> 8], 1);
        __syncthreads();
        for (int i = threadIdx.x; i < NBUK; i += 256) {
            int c = lh[i];
            lbase[i] = c ? (atomicAdd(&bcur[i], c) + i * CAP) : 0;
            lh[i] = 0;                 // reuse as local cursor
        }
        __syncthreads();
        for (int e = base + threadIdx.x; e < end; e += 256) {
            int d = dst[e];
            int s = src[e];            // < 50000 -> fits in 16 bits
            int b = d >> 8;
            int p = atomicAdd(&lh[b], 1);
            staged[lbase[b] + p] = (unsigned int)s | ((unsigned int)(d & 255) << 16);
        }
    } else {
        // ---- GEMM role ----
        const int gb   = blockIdx.x - NBLK;
        const int wid  = threadIdx.x >> 6;
        const int lane = threadIdx.x & 63;
        const int row0 = gb * 64 + wid * 16;
        const int mrow = lane & 15;
        const int kgrp = lane >> 4;          // 0..3

        int arow = row0 + mrow;
        int arow_c = arow < N_NODES ? arow : (N_NODES - 1);
        const float* aptr = feat + (size_t)arow_c * DIM + kgrp * 8;

        const int t = threadIdx.x;
        const int srow = t >> 3;             // base row (stride 32 per iter)
        const int scb  = (t & 7) * 8;        // col offset within quarter

        if (gb == 0) {                       // zero Yc pad rows (4096 elems)
            for (int i = threadIdx.x; i < NCHUNK * 16 * 32; i += 256) {
                int c = i >> 9;
                int rem = i & 511;
                Yc[(size_t)c * NPAD * 32 + (size_t)(N_NODES + (rem >> 5)) * 32 + (rem & 31)]
                    = (__bf16)0.0f;
            }
        }

        f32x4 acc[16];
#pragma unroll
        for (int i = 0; i < 16; ++i) acc[i] = (f32x4)0.0f;

        for (int p = 0; p < 4; ++p) {
            f32x4 ar0 = *(const f32x4*)(aptr + (p * 2) * 32);
            f32x4 ar1 = *(const f32x4*)(aptr + (p * 2) * 32 + 4);
            f32x4 ar2 = *(const f32x4*)(aptr + (p * 2 + 1) * 32);
            f32x4 ar3 = *(const f32x4*)(aptr + (p * 2 + 1) * 32 + 4);

            if (p) __syncthreads();
            // stage W[:, p*64..+64) f32 -> bf16 LDS
#pragma unroll
            for (int i = 0; i < 8; ++i) {
                int row = srow + i * 32;
                const float* wp = W + (size_t)row * DIM + p * 64 + scb;
                f32x4 w0 = *(const f32x4*)(wp);
                f32x4 w1 = *(const f32x4*)(wp + 4);
                bf16x8 wv;
                wv[0] = (__bf16)w0[0]; wv[1] = (__bf16)w0[1];
                wv[2] = (__bf16)w0[2]; wv[3] = (__bf16)w0[3];
                wv[4] = (__bf16)w1[0]; wv[5] = (__bf16)w1[1];
                wv[6] = (__bf16)w1[2]; wv[7] = (__bf16)w1[3];
                *(bf16x8*)(lw + row * LROW + scb) = wv;
            }
            __syncthreads();

            bf16x8 af0, af1;
            af0[0] = (__bf16)ar0[0]; af0[1] = (__bf16)ar0[1];
            af0[2] = (__bf16)ar0[2]; af0[3] = (__bf16)ar0[3];
            af0[4] = (__bf16)ar1[0]; af0[5] = (__bf16)ar1[1];
            af0[6] = (__bf16)ar1[2]; af0[7] = (__bf16)ar1[3];
            af1[0] = (__bf16)ar2[0]; af1[1] = (__bf16)ar2[1];
            af1[2] = (__bf16)ar2[2]; af1[3] = (__bf16)ar2[3];
            af1[4] = (__bf16)ar3[0]; af1[5] = (__bf16)ar3[1];
            af1[6] = (__bf16)ar3[2]; af1[7] = (__bf16)ar3[3];

#pragma unroll
            for (int nt = 0; nt < 16; ++nt) {
                const __bf16* lp = lw + (nt * 16 + mrow) * LROW + kgrp * 8;
                bf16x8 wf0 = *(const bf16x8*)(lp);
                bf16x8 wf1 = *(const bf16x8*)(lp + 32);
                acc[nt] = __builtin_amdgcn_mfma_f32_16x16x32_bf16(wf0, af0, acc[nt], 0, 0, 0);
                acc[nt] = __builtin_amdgcn_mfma_f32_16x16x32_bf16(wf1, af1, acc[nt], 0, 0, 0);
            }
        }

        const int node = row0 + mrow;
        if (node < N_NODES) {
#pragma unroll
            for (int nt = 0; nt < 16; ++nt) {
                int oc0 = nt * 16 + kgrp * 4;
                bf16x4 pv;
                pv[0] = (__bf16)acc[nt][0];
                pv[1] = (__bf16)acc[nt][1];
                pv[2] = (__bf16)acc[nt][2];
                pv[3] = (__bf16)acc[nt][3];
                __bf16* yp = Yc + (size_t)(oc0 >> 5) * NPAD * 32
                                + (size_t)node * 32 + (oc0 & 31);
                *(bf16x4*)yp = pv;
            }
        }
    }
}

// ================= K2: finalize (1024 threads/block, 196 blocks) ==============
// Node offsets/degrees + u16 edge lists, 8-padded with DUMMY.
__global__ __launch_bounds__(1024) void finalize_k(const unsigned int* __restrict__ staged,
                                                   const int* __restrict__ bcur,
                                                   int* __restrict__ offs,
                                                   u16* __restrict__ deg16,
                                                   u16* __restrict__ edge16) {
    __shared__ int nh[256];
    __shared__ int nbase[256];
    __shared__ int sm[256];
    int t = threadIdx.x, b = blockIdx.x;
    int beg = b * CAP;
    int cnt = bcur[b];
    if (t < 256) nh[t] = 0;
    __syncthreads();
    for (int i = t; i < cnt; i += 1024)
        atomicAdd(&nh[staged[beg + i] >> 16], 1);
    __syncthreads();
    int v = (t < 256) ? nh[t] : 0;
    int v8 = (v + 7) & ~7;         // padded count (multiple of 8)
    if (t < 256) sm[t] = v8;
    __syncthreads();
    for (int off = 1; off < 256; off <<= 1) {
        int x = (t < 256 && t >= off) ? sm[t - off] : 0;
        __syncthreads();
        if (t < 256) sm[t] += x;
        __syncthreads();
    }
    if (t < 256) {
        nbase[t] = sm[t] - v8;
        int node = (b << 8) + t;
        if (node < N_NODES) {
            offs[node]  = beg + nbase[t];
            deg16[node] = (u16)v;
        }
        for (int i = v; i < v8; ++i)
            edge16[beg + nbase[t] + i] = (u16)DUMMY;
        nh[t] = 0;                 // reuse as per-node cursor
    }
    __syncthreads();
    for (int i = t; i < cnt; i += 1024) {
        unsigned int u = staged[beg + i];
        int dl = (int)(u >> 16);
        int p = atomicAdd(&nh[dl], 1);
        edge16[beg + nbase[dl] + p] = (u16)(u & 0xFFFFu);
    }
}

// ================= K3: gather-mean + bias, dot2-accumulate ====================
// chunk = blockIdx & 7 (XCD round-robin); per-XCD working set = 3.2MB (L2-resident)
// wave = 16 nodes; segment (4 lanes) owns one node; lane covers 8 cols (16B/edge).
// Edge PAIRS: v_perm packs [e0.colC : e1.colC]; v_dot2_f32_bf16 with (1,1) adds
// both to the f32 accumulator -- 16 VALU ops per 2 edges vs 24 for shift/add.
#define GQ(ev) (*(const uint4*)(Ybase + (size_t)((u32)(ev) & 0xffffu) * 32 + cl))
#define DOT2A(acc, p) \
    asm("v_dot2_f32_bf16 %0, %1, %2, %0" : "+v"(acc) : "v"(p), "v"(ones2))
#define ACCP(qx, qy) do { \
    u32 p_; \
    p_ = __builtin_amdgcn_perm((qx).x, (qy).x, 0x05040100u); DOT2A(a0, p_); \
    p_ = __builtin_amdgcn_perm((qx).x, (qy).x, 0x07060302u); DOT2A(a1, p_); \
    p_ = __builtin_amdgcn_perm((qx).y, (qy).y, 0x05040100u); DOT2A(a2, p_); \
    p_ = __builtin_amdgcn_perm((qx).y, (qy).y, 0x07060302u); DOT2A(a3, p_); \
    p_ = __builtin_amdgcn_perm((qx).z, (qy).z, 0x05040100u); DOT2A(a4, p_); \
    p_ = __builtin_amdgcn_perm((qx).z, (qy).z, 0x07060302u); DOT2A(a5, p_); \
    p_ = __builtin_amdgcn_perm((qx).w, (qy).w, 0x05040100u); DOT2A(a6, p_); \
    p_ = __builtin_amdgcn_perm((qx).w, (qy).w, 0x07060302u); DOT2A(a7, p_); \
} while (0)

__global__ __launch_bounds__(256) void aggregate_k(const __bf16* __restrict__ Yc,
                                                   const int* __restrict__ offs,
                                                   const u16* __restrict__ deg16,
                                                   const u16* __restrict__ edge16,
                                                   const float* __restrict__ bias,
                                                   float* __restrict__ out) {
    const int chunk = blockIdx.x & 7;
    const int bic   = blockIdx.x >> 3;      // block index within chunk
    const int wid   = threadIdx.x >> 6;
    const int lane  = threadIdx.x & 63;
    const int seg   = lane >> 2;            // node slot 0..15
    const int cl    = (lane & 3) * 8;       // bf16 col within chunk: 0,8,16,24

    const int g = bic * 4 + wid;            // one group per warp
    if (g >= NGROUP) return;
    const int node = g * 16 + seg;

    const __bf16* Ybase = Yc + (size_t)chunk * NPAD * 32;
    const float* bp = bias + chunk * 32 + cl;
    const f32x4 bv0 = *(const f32x4*)bp;
    const f32x4 bv1 = *(const f32x4*)(bp + 4);

    const int beg = offs[node];
    const int dg  = (int)deg16[node];

    float a0 = 0.f, a1 = 0.f, a2 = 0.f, a3 = 0.f;
    float a4 = 0.f, a5 = 0.f, a6 = 0.f, a7 = 0.f;
    u32 ones2 = 0x3F803F80u;                // bf16 (1.0, 1.0)

    f32x4 r0, r1;
    if (dg > 0) {
        const int nb8 = (dg + 7) >> 3;      // number of 8-edge batches
        const int npair = nb8 >> 1;
        const int odd = nb8 & 1;
        int j = beg;
        u64 eA = *(const u64*)(edge16 + j);
        u64 eB = *(const u64*)(edge16 + j + 4);
        u64 eC = *(const u64*)(edge16 + j + 8);
        u64 eD = *(const u64*)(edge16 + j + 12);
        for (int p = 0; p < npair; ++p) {
            u64 nA = *(const u64*)(edge16 + j + 16);
            u64 nB = *(const u64*)(edge16 + j + 20);
            u64 nC = *(const u64*)(edge16 + j + 24);
            u64 nD = *(const u64*)(edge16 + j + 28);
            uint4 q0 = GQ(eA);       uint4 q1 = GQ(eA >> 16);
            uint4 q2 = GQ(eA >> 32); uint4 q3 = GQ(eA >> 48);
            uint4 q4 = GQ(eB);       uint4 q5 = GQ(eB >> 16);
            uint4 q6 = GQ(eB >> 32); uint4 q7 = GQ(eB >> 48);
            uint4 q8 = GQ(eC);       uint4 q9 = GQ(eC >> 16);
            uint4 qa = GQ(eC >> 32); uint4 qb = GQ(eC >> 48);
            uint4 qc = GQ(eD);       uint4 qd = GQ(eD >> 16);
            uint4 qe = GQ(eD >> 32); uint4 qf = GQ(eD >> 48);
            ACCP(q0, q1); ACCP(q2, q3); ACCP(q4, q5); ACCP(q6, q7);
            ACCP(q8, q9); ACCP(qa, qb); ACCP(qc, qd); ACCP(qe, qf);
            j += 16;
            eA = nA; eB = nB; eC = nC; eD = nD;
        }
        if (odd) {
            uint4 q0 = GQ(eA);       uint4 q1 = GQ(eA >> 16);
            uint4 q2 = GQ(eA >> 32); uint4 q3 = GQ(eA >> 48);
            uint4 q4 = GQ(eB);       uint4 q5 = GQ(eB >> 16);
            uint4 q6 = GQ(eB >> 32); uint4 q7 = GQ(eB >> 48);
            ACCP(q0, q1); ACCP(q2, q3); ACCP(q4, q5); ACCP(q6, q7);
        }
        float inv = 1.0f / (float)dg;
        r0[0] = a0 * inv + bv0[0];
        r0[1] = a1 * inv + bv0[1];
        r0[2] = a2 * inv + bv0[2];
        r0[3] = a3 * inv + bv0[3];
        r1[0] = a4 * inv + bv1[0];
        r1[1] = a5 * inv + bv1[1];
        r1[2] = a6 * inv + bv1[2];
        r1[3] = a7 * inv + bv1[3];
    } else {
        uint4 q = *(const uint4*)(Ybase + (size_t)node * 32 + cl);
        r0[0] = __uint_as_float(q.x << 16) + bv0[0];
        r0[1] = __uint_as_float(q.x & 0xffff0000u) + bv0[1];
        r0[2] = __uint_as_float(q.y << 16) + bv0[2];
        r0[3] = __uint_as_float(q.y & 0xffff0000u) + bv0[3];
        r1[0] = __uint_as_float(q.z << 16) + bv1[0];
        r1[1] = __uint_as_float(q.z & 0xffff0000u) + bv1[1];
        r1[2] = __uint_as_float(q.w << 16) + bv1[2];
        r1[3] = __uint_as_float(q.w & 0xffff0000u) + bv1[3];
    }
    float* op = out + (size_t)node * DIM + chunk * 32 + cl;
    *(f32x4*)op = r0;
    *(f32x4*)(op + 4) = r1;
}

static inline size_t align64(size_t x) { return (x + 63) & ~(size_t)63; }

extern "C" void kernel_launch(void* const* d_in, const int* in_sizes, int n_in,
                              void* d_out, int out_size, void* d_ws, size_t ws_size,
                              hipStream_t stream) {
    const float* feature = (const float*)d_in[0];
    const int*   src     = (const int*)d_in[1];
    const int*   dst     = (const int*)d_in[2];
    const float* W       = (const float*)d_in[3];
    const float* b       = (const float*)d_in[4];
    float* out = (float*)d_out;

    // workspace layout (~38.2 MB total)
    char* ws = (char*)d_ws;
    __bf16* Yc  = (__bf16*)ws;               ws += align64((size_t)NCHUNK * NPAD * 32 * 2);
    int* offs     = (int*)ws;                ws += align64((size_t)N_NODES * 4);
    u16* deg16    = (u16*)ws;                ws += align64((size_t)N_NODES * 2);
    int* bcur     = (int*)ws;                ws += align64((size_t)NBUK * 4);
    unsigned int* staged = (unsigned int*)ws; ws += align64((size_t)NBUK * CAP * 4);
    u16* edge16   = (u16*)ws;                ws += align64((size_t)NBUK * CAP * 2 + 128);

    hipMemsetAsync(bcur, 0, (size_t)NBUK * 4, stream);
    k1_k<<<NBLK + GEMM_BLKS, 256, 0, stream>>>(feature, W, Yc, src, dst, bcur, staged);
    finalize_k<<<NBUK, 1024, 0, stream>>>(staged, bcur, offs, deg16, edge16);
    aggregate_k<<<NCHUNK * AGG_BPC, 256, 0, stream>>>(Yc, offs, deg16, edge16, b, out);
}